// Round 11
// baseline (116.387 us; speedup 1.0000x reference)
//
#include <hip/hip_runtime.h>
#include <math.h>

#define NUM_E   100000
#define GAMMA_F 12.0f
#define EMB_RANGE_F 0.21875f                       // (12+2)/64
#define INV_TWO_EMB (1.0f / (2.0f * EMB_RANGE_F))  // rev = r * this = phase/(2pi)

#define TILE_E  16                                 // entities per LDS tile (8 KB)
#define NT      (NUM_E / TILE_E)                   // 6250 tiles exactly
#define GRID    2048                               // 8 blocks/CU exactly

typedef float v4f __attribute__((ext_vector_type(4)));
typedef float v2f __attribute__((ext_vector_type(2)));

// ---- packed-f32 VALU (VOP3P): 2 dims per instruction ----
static __device__ __forceinline__ v2f pk_sub(v2f a, v2f b) {
    v2f d;
    asm("v_pk_add_f32 %0, %1, %2 neg_lo:[0,1] neg_hi:[0,1]"
        : "=v"(d) : "v"(a), "v"(b));
    return d;
}
static __device__ __forceinline__ v2f pk_mul(v2f a, v2f b) {
    v2f d;
    asm("v_pk_mul_f32 %0, %1, %2" : "=v"(d) : "v"(a), "v"(b));
    return d;
}
static __device__ __forceinline__ v2f pk_fma(v2f a, v2f b, v2f c) {
    v2f d;
    asm("v_pk_fma_f32 %0, %1, %2, %3" : "=v"(d) : "v"(a), "v"(b), "v"(c));
    return d;
}
static __device__ __forceinline__ float sq2(v2f dx, v2f dy) {
    v2f sq = pk_fma(dy, dy, pk_mul(dx, dx));
    return __builtin_amdgcn_sqrtf(sq.x) + __builtin_amdgcn_sqrtf(sq.y);
}
static __device__ __forceinline__ v2f lo2(v4f v) { return __builtin_shufflevector(v, v, 0, 1); }
static __device__ __forceinline__ v2f hi2(v4f v) { return __builtin_shufflevector(v, v, 2, 3); }

// cross-lane add via DPP (VALU pipe, no DS, no lgkm wait)
// 0xB1 = quad_perm [1,0,3,2] (xor1), 0x4E = quad_perm [2,3,0,1] (xor2),
// 0x141 = row_half_mirror: after xor1+xor2 it adds the other quad of the
// aligned 8-lane group. Verified passing R8-R16.
template <int CTRL>
static __device__ __forceinline__ float dpp_xor_add(float x) {
    int y = __builtin_amdgcn_update_dpp(0, __float_as_int(x), CTRL, 0xF, 0xF, true);
    return x + __int_as_float(y);
}

// async global->LDS DMA, width 16: 64 lanes x 16B = 1 KB per instruction.
// g is the PER-LANE source (base + lane*16B); l is the WAVE-UNIFORM LDS base
// (HW adds lane*16B). No destination register -> the allocator cannot sink or
// compress this pipeline (the R11-R14 failure mode).
static __device__ __forceinline__ void stage_chunk(const float* g, float* l) {
    __builtin_amdgcn_global_load_lds(
        (const __attribute__((address_space(1))) void*)g,
        (__attribute__((address_space(3))) void*)l,
        16, 0, 0);
}

// build this lane's rot slice for one batch (8 dims x {re,im} = 16 f32).
// Produced by v_sin/v_cos chains -> NOT rematerializable (unlike R10's
// LDS-sourced table): the allocator must keep it resident.
static __device__ __forceinline__ void make_rot(
        const int* __restrict__ facts, const float* __restrict__ ent,
        const float* __restrict__ rel, int b, int dg, v2f RR[4], v2f RI[4]) {
    const int f0 = facts[b * 3 + 0];
    const int f1 = facts[b * 3 + 1];
    const float* hp = ent + (size_t)f0 * 128 + dg * 8;
    const float* rp = rel + (size_t)f1 * 64  + dg * 8;
    v4f hre0 = *(const v4f*)(hp);
    v4f hre1 = *(const v4f*)(hp + 4);
    v4f him0 = *(const v4f*)(hp + 64);
    v4f him1 = *(const v4f*)(hp + 68);
    v4f ph0  = *(const v4f*)(rp);
    v4f ph1  = *(const v4f*)(rp + 4);
    v4f rr0, rr1, ri0, ri1;
#pragma unroll
    for (int j = 0; j < 4; ++j) {
        float rev0 = ph0[j] * INV_TWO_EMB;       // phase/(2pi) in [-0.5,0.5]
        float s0 = __builtin_amdgcn_sinf(rev0);  // v_sin_f32: revolutions
        float c0 = __builtin_amdgcn_cosf(rev0);
        rr0[j] = hre0[j] * c0 - him0[j] * s0;
        ri0[j] = hre0[j] * s0 + him0[j] * c0;
        float rev1 = ph1[j] * INV_TWO_EMB;
        float s1 = __builtin_amdgcn_sinf(rev1);
        float c1 = __builtin_amdgcn_cosf(rev1);
        rr1[j] = hre1[j] * c1 - him1[j] * s1;
        ri1[j] = hre1[j] * s1 + him1[j] * c1;
    }
    RR[0] = lo2(rr0); RR[1] = hi2(rr0); RR[2] = lo2(rr1); RR[3] = hi2(rr1);
    RI[0] = lo2(ri0); RI[1] = hi2(ri0); RI[2] = lo2(ri1); RI[3] = hi2(ri1);
}

// R17 = R15 structure + 2-batches-per-lane register reuse.
// R16 verdict: 1-entity LDS-read lookahead moved only +1.4% -> latency was
// not the stall. The binder is LDS PIPE THROUGHPUT: the old decomposition
// costs an invariant 256 ds_read_b128/tile (each entity value feeds ONE
// output); per CU = 24.4 tiles x 256 x ~10cy = ~25-31us of LDS-pipe
// occupancy inside the 43us wall.
// Fix: lane (bq,dg) holds rot for TWO batches (b0=bh*16+bq, b1=b0+8; 32 f32,
// sin/cos-produced = non-rematerializable). Each 64B entity read now feeds
// two outputs -> 128 reads/tile (HALVED). Wave wv=(bh,eh) covers 16 batches
// x 8 entities. VALU/trans totals invariant; all three pipes land ~10-16us.
// No register lookahead (R16 proved it ~moot); live set ~70 VGPR.
__global__ __launch_bounds__(256, 2) void rotate_dist_fused(
        const int*   __restrict__ facts,
        const float* __restrict__ ent,
        const float* __restrict__ rel,
        float*       __restrict__ out) {
    __shared__ __align__(16) float sbuf[2][TILE_E * 128];   // 2 x 8 KB

    const int t    = threadIdx.x;
    const int lane = t & 63;
    const int wv   = t >> 6;
    const int bq   = lane >> 3;         // batch-in-half 0..7
    const int dg   = lane & 7;          // dims 8dg..8dg+7
    const int eh   = wv & 1;            // entity half: entities eh*8..eh*8+7
    const int bh   = wv >> 1;           // batch half
    const int b0   = bh * 16 + bq;      // this lane's two batches
    const int b1   = b0 + 8;

    int tile = blockIdx.x;

    // ---- stage first tile into buf0 (latency hides under the prologue) ----
    {
        const float* g = ent + (size_t)tile * (TILE_E * 128) + wv * 512 + lane * 4;
        float* l = &sbuf[0][wv * 512];
        stage_chunk(g, l);
        stage_chunk(g + 256, l + 256);
    }

    // ---- rot slices for both batches (32 f32, register-resident) ----
    v2f RR0[4], RI0[4], RR1[4], RI1[4];
    make_rot(facts, ent, rel, b0, dg, RR0, RI0);
    make_rot(facts, ent, rel, b1, dg, RR1, RI1);

    float* orow0 = out + (size_t)b0 * NUM_E;
    float* orow1 = out + (size_t)b1 * NUM_E;

    int cur = 0;
    __syncthreads();        // buf0 landed (barrier drains vmcnt)

    while (true) {
        const int nxt = tile + GRID;
        if (nxt < NT) {     // issue next-tile DMA before computing current
            const float* g = ent + (size_t)nxt * (TILE_E * 128) + wv * 512 + lane * 4;
            float* l = &sbuf[cur ^ 1][wv * 512];
            stage_chunk(g, l);
            stage_chunk(g + 256, l + 256);
        }

        // ---- compute this wave's 8-entity half against its 16 batches ----
        const float* csrc = &sbuf[cur][0] + eh * (8 * 128) + dg * 8;
        const int ebase = tile * TILE_E + eh * 8;

#pragma unroll
        for (int q = 0; q < 2; ++q) {
            v4f vout0, vout1;
#pragma unroll
            for (int i = 0; i < 4; ++i) {
                const float* ep = csrc + (q * 4 + i) * 128;
                v4f er0 = *(const v4f*)(ep);         // ds_read_b128, 8-lane bcast
                v4f er1 = *(const v4f*)(ep + 4);
                v4f ei0 = *(const v4f*)(ep + 64);
                v4f ei1 = *(const v4f*)(ep + 68);
                v2f e2[4] = { lo2(er0), hi2(er0), lo2(er1), hi2(er1) };
                v2f i2[4] = { lo2(ei0), hi2(ei0), lo2(ei1), hi2(ei1) };
                // batch b0
                float v0 = (sq2(pk_sub(RR0[0], e2[0]), pk_sub(RI0[0], i2[0]))
                          + sq2(pk_sub(RR0[1], e2[1]), pk_sub(RI0[1], i2[1])))
                         + (sq2(pk_sub(RR0[2], e2[2]), pk_sub(RI0[2], i2[2]))
                          + sq2(pk_sub(RR0[3], e2[3]), pk_sub(RI0[3], i2[3])));
                // batch b1 (reuses e2/i2 registers)
                float v1 = (sq2(pk_sub(RR1[0], e2[0]), pk_sub(RI1[0], i2[0]))
                          + sq2(pk_sub(RR1[1], e2[1]), pk_sub(RI1[1], i2[1])))
                         + (sq2(pk_sub(RR1[2], e2[2]), pk_sub(RI1[2], i2[2]))
                          + sq2(pk_sub(RR1[3], e2[3]), pk_sub(RI1[3], i2[3])));
                // interleaved DPP reduces (two independent chains -> ILP)
                v0 = dpp_xor_add<0xB1>(v0);  v1 = dpp_xor_add<0xB1>(v1);
                v0 = dpp_xor_add<0x4E>(v0);  v1 = dpp_xor_add<0x4E>(v1);
                v0 = dpp_xor_add<0x141>(v0); v1 = dpp_xor_add<0x141>(v1);
                vout0[i] = GAMMA_F - v0;
                vout1[i] = GAMMA_F - v1;
            }
            // all 8 dg lanes hold both results; pick disjoint storing lanes:
            // dg==q   -> batch b0's 16B segment, dg==q+4 -> batch b1's
            if (dg == q)     *(v4f*)(orow0 + ebase + q * 4) = vout0;
            if (dg == q + 4) *(v4f*)(orow1 + ebase + q * 4) = vout1;
        }

        if (nxt >= NT) break;
        __syncthreads();    // next buf landed; everyone done reading cur
        cur ^= 1;
        tile = nxt;
    }
}

extern "C" void kernel_launch(void* const* d_in, const int* in_sizes, int n_in,
                              void* d_out, int out_size, void* d_ws, size_t ws_size,
                              hipStream_t stream) {
    const int*   facts = (const int*)d_in[0];
    const float* ent   = (const float*)d_in[1];
    const float* rel   = (const float*)d_in[2];
    float*       out   = (float*)d_out;
    (void)d_ws; (void)ws_size;

    rotate_dist_fused<<<dim3(GRID), dim3(256), 0, stream>>>(facts, ent, rel, out);
}